// Round 1
// baseline (1365.513 us; speedup 1.0000x reference)
//
#include <hip/hip_runtime.h>
#include <hip/hip_bf16.h>

#define TT 96
#define BB 32
#define DIN 256
#define HH 512
#define VV 128

// ---------------- Phase A: Z[t][g][h][b] = sum_d x[b][t][d] * Wg[t][h][d] ----------------
// grid: 96*4*8 blocks (t, g, h-tile of 64), 256 threads
__global__ __launch_bounds__(256) void phaseA_kernel(
    const float* __restrict__ x,
    const float* __restrict__ Wf, const float* __restrict__ Wi,
    const float* __restrict__ Wc, const float* __restrict__ Wo,
    float* __restrict__ Z)
{
    int bid = blockIdx.x;
    int t  = bid >> 5;          // /32  (4 gates * 8 tiles)
    int g  = (bid >> 3) & 3;
    int h0 = (bid & 7) << 6;    // *64
    const float* W = (g == 0) ? Wf : (g == 1) ? Wi : (g == 2) ? Wc : Wo;

    __shared__ float Ws[64][65];   // padded stride -> conflict-free reads
    __shared__ float Xs[32][64];

    int tid = threadIdx.x;
    int h  = tid & 63;
    int bg = tid >> 6;            // 4 groups of 8 batch elems
    float acc[8] = {0.f,0.f,0.f,0.f,0.f,0.f,0.f,0.f};

    for (int dc = 0; dc < 4; ++dc) {
        int d0 = dc * 64;
        // stage W chunk [64h][64d]
        {
            int r  = tid >> 2;         // row 0..63
            int c4 = tid & 3;          // 4 threads per row
            const float* src = W + ((size_t)(t * HH + h0 + r)) * DIN + d0;
            #pragma unroll
            for (int j = 0; j < 4; ++j) {
                int cc = (c4 + j * 4) * 4;
                float4 v = *reinterpret_cast<const float4*>(src + cc);
                Ws[r][cc + 0] = v.x; Ws[r][cc + 1] = v.y;
                Ws[r][cc + 2] = v.z; Ws[r][cc + 3] = v.w;
            }
        }
        // stage x chunk [32b][64d]
        {
            int b  = tid >> 3;         // 0..31
            int c8 = tid & 7;          // 8 threads per row, 8 floats each
            const float* src = x + ((size_t)(b * TT + t)) * DIN + d0 + c8 * 8;
            float4 v0 = *reinterpret_cast<const float4*>(src);
            float4 v1 = *reinterpret_cast<const float4*>(src + 4);
            *reinterpret_cast<float4*>(&Xs[b][c8 * 8])     = v0;
            *reinterpret_cast<float4*>(&Xs[b][c8 * 8 + 4]) = v1;
        }
        __syncthreads();
        #pragma unroll 8
        for (int d = 0; d < 64; ++d) {
            float w = Ws[h][d];
            #pragma unroll
            for (int bb = 0; bb < 8; ++bb)
                acc[bb] = fmaf(w, Xs[bg * 8 + bb][d], acc[bb]);
        }
        __syncthreads();
    }
    float* dst = Z + ((size_t)(t * 4 + g) * HH + h0 + h) * BB + bg * 8;
    #pragma unroll
    for (int bb = 0; bb < 8; ++bb) dst[bb] = acc[bb];
}

// ---------------- Phase B: one timestep ----------------
// grid: 256 blocks (2 h-rows each), 512 threads (2-way k split * 4 gates * 2 h * 32 b)
__global__ __launch_bounds__(512) void lstm_step_kernel(
    const float* __restrict__ Whf, const float* __restrict__ Whi,
    const float* __restrict__ Whc, const float* __restrict__ Who,
    const float* __restrict__ bf,  const float* __restrict__ bi,
    const float* __restrict__ bc,  const float* __restrict__ bo,
    const float* __restrict__ Z,   float* __restrict__ C,
    float* __restrict__ Hall, int t)
{
    int tid = threadIdx.x;
    int h0 = blockIdx.x * 2;

    __shared__ float pre[2][4][64];   // [ksplit][gate][hh*32+b]

    int ks = tid >> 8;         // 0/1
    int g  = (tid >> 6) & 3;   // gate
    int hb = tid & 63;         // hh*32 + b
    int b  = hb & 31;
    int hh = hb >> 5;
    int h  = h0 + hh;

    float acc = 0.f;
    if (t > 0) {
        const float* W = (g == 0) ? Whf : (g == 1) ? Whi : (g == 2) ? Whc : Who;
        const float* wrow = W + ((size_t)t * HH + h) * HH + ks * 256;
        const float* hrow = Hall + ((size_t)(t - 1)) * HH * BB + (size_t)(ks * 256) * BB + b;
        float a0 = 0.f, a1 = 0.f;
        #pragma unroll 8
        for (int k = 0; k < 256; k += 2) {
            a0 = fmaf(wrow[k],     hrow[(size_t)k * BB],       a0);
            a1 = fmaf(wrow[k + 1], hrow[(size_t)(k + 1) * BB], a1);
        }
        acc = a0 + a1;
    }
    pre[ks][g][hb] = acc;
    __syncthreads();

    if (tid < 64) {
        int hh2 = tid >> 5, b2 = tid & 31;
        int h2 = h0 + hh2;
        float pf = Z[((size_t)(t * 4 + 0) * HH + h2) * BB + b2];
        float pi = Z[((size_t)(t * 4 + 1) * HH + h2) * BB + b2];
        float pc = Z[((size_t)(t * 4 + 2) * HH + h2) * BB + b2];
        float po = Z[((size_t)(t * 4 + 3) * HH + h2) * BB + b2];
        if (t > 0) {
            pf += pre[0][0][tid] + pre[1][0][tid] + bf[t * HH + h2];
            pi += pre[0][1][tid] + pre[1][1][tid] + bi[t * HH + h2];
            pc += pre[0][2][tid] + pre[1][2][tid] + bc[t * HH + h2];
            po += pre[0][3][tid] + pre[1][3][tid] + bo[t * HH + h2];
        }
        float f  = 1.f / (1.f + __expf(-pf));
        float i  = 1.f / (1.f + __expf(-pi));
        float cb = tanhf(pc);
        float o  = 1.f / (1.f + __expf(-po));
        float cold = (t > 0) ? C[h2 * BB + b2] : 0.f;
        float cn = f * cold + i * cb;
        C[h2 * BB + b2] = cn;
        float hn = o * tanhf(cn);
        Hall[((size_t)t * HH + h2) * BB + b2] = hn;
    }
}

// ---------------- Phase C: logits[b][t][v] = Hall[t][:][b] . lin_w[t][v][:] + lin_b[t][v] ----
// grid: 96*4 blocks (t, v-tile of 32), 256 threads (32 v * 8 b-groups of 4)
__global__ __launch_bounds__(256) void phaseC_kernel(
    const float* __restrict__ lw, const float* __restrict__ lb,
    const float* __restrict__ Hall, float* __restrict__ out)
{
    int t  = blockIdx.x >> 2;
    int v0 = (blockIdx.x & 3) << 5;
    int tid = threadIdx.x;
    int v  = v0 + (tid >> 3);
    int bg = tid & 7;
    const float* w  = lw + ((size_t)t * VV + v) * HH;
    const float* hp = Hall + (size_t)t * HH * BB;
    float acc0 = 0.f, acc1 = 0.f, acc2 = 0.f, acc3 = 0.f;
    #pragma unroll 4
    for (int k = 0; k < HH; ++k) {
        float wv = w[k];
        float4 hv = *reinterpret_cast<const float4*>(hp + (size_t)k * BB + bg * 4);
        acc0 = fmaf(wv, hv.x, acc0);
        acc1 = fmaf(wv, hv.y, acc1);
        acc2 = fmaf(wv, hv.z, acc2);
        acc3 = fmaf(wv, hv.w, acc3);
    }
    float bias = lb[t * VV + v];
    float r[4] = {acc0 + bias, acc1 + bias, acc2 + bias, acc3 + bias};
    #pragma unroll
    for (int j = 0; j < 4; ++j) {
        int b = bg * 4 + j;
        out[((size_t)b * TT + t) * VV + v] = r[j];
    }
}

extern "C" void kernel_launch(void* const* d_in, const int* in_sizes, int n_in,
                              void* d_out, int out_size, void* d_ws, size_t ws_size,
                              hipStream_t stream)
{
    const float* x     = (const float*)d_in[0];
    const float* Wif   = (const float*)d_in[1];
    const float* Wii   = (const float*)d_in[2];
    const float* Wic   = (const float*)d_in[3];
    const float* Wio   = (const float*)d_in[4];
    const float* Whf_w = (const float*)d_in[5];
    const float* Whf_b = (const float*)d_in[6];
    const float* Whi_w = (const float*)d_in[7];
    const float* Whi_b = (const float*)d_in[8];
    const float* Whc_w = (const float*)d_in[9];
    const float* Whc_b = (const float*)d_in[10];
    const float* Who_w = (const float*)d_in[11];
    const float* Who_b = (const float*)d_in[12];
    const float* lin_w = (const float*)d_in[13];
    const float* lin_b = (const float*)d_in[14];
    float* out = (float*)d_out;

    float* Z    = (float*)d_ws;                              // 96*4*512*32 floats
    float* Hall = Z + (size_t)TT * 4 * HH * BB;              // 96*512*32 floats
    float* C    = Hall + (size_t)TT * HH * BB;               // 512*32 floats

    phaseA_kernel<<<dim3(TT * 4 * 8), dim3(256), 0, stream>>>(x, Wif, Wii, Wic, Wio, Z);

    for (int t = 0; t < TT; ++t) {
        lstm_step_kernel<<<dim3(256), dim3(512), 0, stream>>>(
            Whf_w, Whi_w, Whc_w, Who_w, Whf_b, Whi_b, Whc_b, Who_b, Z, C, Hall, t);
    }

    phaseC_kernel<<<dim3(TT * 4), dim3(256), 0, stream>>>(lin_w, lin_b, Hall, out);
}

// Round 2
// 933.116 us; speedup vs baseline: 1.4634x; 1.4634x over previous
//
#include <hip/hip_runtime.h>
#include <hip/hip_bf16.h>

#define TT 96
#define BB 32
#define DIN 256
#define HH 512
#define VV 128

// ---------------- Phase A: Z[t][g][h][b] = sum_d x[b][t][d] * Wg[t][h][d] ----------------
// grid: 96 t * 16 tiles (gate, 128-row block), 256 threads.
// W streamed global->regs (no reuse); x staged in LDS with XOR-quad swizzle.
__global__ __launch_bounds__(256, 4) void phaseA_kernel(
    const float* __restrict__ x,
    const float* __restrict__ Wf, const float* __restrict__ Wi,
    const float* __restrict__ Wc, const float* __restrict__ Wo,
    float* __restrict__ Z)
{
    int bid  = blockIdx.x;
    int t    = bid >> 4;
    int tile = bid & 15;
    int g    = tile >> 2;
    int h0   = (tile & 3) * 128;
    const float* W = (g == 0) ? Wf : (g == 1) ? Wi : (g == 2) ? Wc : Wo;

    __shared__ float4 Xs4[32 * 64];   // 32 KB, element (b, kquad q) at [b*64 + (q ^ (b&15))]

    int tid = threadIdx.x;
    // stage x[b][t][0..255]
    {
        int b   = tid >> 3;
        int kq8 = tid & 7;
        const float* src = x + ((size_t)b * TT + t) * DIN;
        int bx = b & 15;
        #pragma unroll
        for (int j = 0; j < 8; ++j) {
            int q = kq8 * 8 + j;
            float4 v = *reinterpret_cast<const float4*>(src + q * 4);
            Xs4[b * 64 + (q ^ bx)] = v;
        }
    }
    __syncthreads();

    int rg = tid >> 3;          // 32 row-groups of 4 rows
    int bg = tid & 7;           // b = c*8 + bg, c = 0..3
    const float* wr = W + ((size_t)t * HH + h0 + rg * 4) * DIN;

    float acc[4][4];
    #pragma unroll
    for (int r = 0; r < 4; ++r)
        #pragma unroll
        for (int c = 0; c < 4; ++c) acc[r][c] = 0.f;

    #pragma unroll 4
    for (int q = 0; q < 64; ++q) {
        float4 xv[4];
        #pragma unroll
        for (int c = 0; c < 4; ++c) {
            int b = c * 8 + bg;
            xv[c] = Xs4[b * 64 + (q ^ (b & 15))];
        }
        #pragma unroll
        for (int r = 0; r < 4; ++r) {
            float4 w = *reinterpret_cast<const float4*>(wr + (size_t)r * DIN + q * 4);
            #pragma unroll
            for (int c = 0; c < 4; ++c) {
                acc[r][c] = fmaf(w.x, xv[c].x, acc[r][c]);
                acc[r][c] = fmaf(w.y, xv[c].y, acc[r][c]);
                acc[r][c] = fmaf(w.z, xv[c].z, acc[r][c]);
                acc[r][c] = fmaf(w.w, xv[c].w, acc[r][c]);
            }
        }
    }

    size_t zbase = ((size_t)(t * 4 + g) * HH + h0 + rg * 4) * BB;
    #pragma unroll
    for (int r = 0; r < 4; ++r)
        #pragma unroll
        for (int c = 0; c < 4; ++c)
            Z[zbase + (size_t)r * BB + c * 8 + bg] = acc[r][c];
}

// ---------------- Phase B: one timestep ----------------
// grid: 512 blocks (1 h-row, all 4 gates), 256 threads = 16 k-splits * 16 b-pairs.
// Weights streamed global->regs float4 (coalescer dedups the 16-lane broadcast).
__global__ __launch_bounds__(256) void lstm_step_kernel(
    const float* __restrict__ Whf, const float* __restrict__ Whi,
    const float* __restrict__ Whc, const float* __restrict__ Who,
    const float* __restrict__ bf,  const float* __restrict__ bi,
    const float* __restrict__ bc,  const float* __restrict__ bo,
    const float* __restrict__ Z,   float* __restrict__ C,
    float* __restrict__ Hall, int t)
{
    int h   = blockIdx.x;
    int tid = threadIdx.x;
    int ks  = tid >> 4;          // 0..15, k-chunk of 32
    int bg  = tid & 15;          // b = 2bg, 2bg+1

    __shared__ float pre[16][4][32];   // 8 KB
    __shared__ float act[4][32];

    float a[4][2];
    #pragma unroll
    for (int gg = 0; gg < 4; ++gg) { a[gg][0] = 0.f; a[gg][1] = 0.f; }

    if (t > 0) {
        int k0 = ks * 32;
        const float* hp = Hall + (size_t)(t - 1) * HH * BB + (size_t)k0 * BB + 2 * bg;
        size_t wo = ((size_t)t * HH + h) * HH + k0;
        const float* wF = Whf + wo;
        const float* wI = Whi + wo;
        const float* wC = Whc + wo;
        const float* wO = Who + wo;
        #pragma unroll
        for (int q = 0; q < 8; ++q) {
            float2 h0v = *reinterpret_cast<const float2*>(hp + (size_t)(q * 4 + 0) * BB);
            float2 h1v = *reinterpret_cast<const float2*>(hp + (size_t)(q * 4 + 1) * BB);
            float2 h2v = *reinterpret_cast<const float2*>(hp + (size_t)(q * 4 + 2) * BB);
            float2 h3v = *reinterpret_cast<const float2*>(hp + (size_t)(q * 4 + 3) * BB);
            float4 w;
            w = *reinterpret_cast<const float4*>(wF + q * 4);
            a[0][0] = fmaf(w.x, h0v.x, a[0][0]); a[0][1] = fmaf(w.x, h0v.y, a[0][1]);
            a[0][0] = fmaf(w.y, h1v.x, a[0][0]); a[0][1] = fmaf(w.y, h1v.y, a[0][1]);
            a[0][0] = fmaf(w.z, h2v.x, a[0][0]); a[0][1] = fmaf(w.z, h2v.y, a[0][1]);
            a[0][0] = fmaf(w.w, h3v.x, a[0][0]); a[0][1] = fmaf(w.w, h3v.y, a[0][1]);
            w = *reinterpret_cast<const float4*>(wI + q * 4);
            a[1][0] = fmaf(w.x, h0v.x, a[1][0]); a[1][1] = fmaf(w.x, h0v.y, a[1][1]);
            a[1][0] = fmaf(w.y, h1v.x, a[1][0]); a[1][1] = fmaf(w.y, h1v.y, a[1][1]);
            a[1][0] = fmaf(w.z, h2v.x, a[1][0]); a[1][1] = fmaf(w.z, h2v.y, a[1][1]);
            a[1][0] = fmaf(w.w, h3v.x, a[1][0]); a[1][1] = fmaf(w.w, h3v.y, a[1][1]);
            w = *reinterpret_cast<const float4*>(wC + q * 4);
            a[2][0] = fmaf(w.x, h0v.x, a[2][0]); a[2][1] = fmaf(w.x, h0v.y, a[2][1]);
            a[2][0] = fmaf(w.y, h1v.x, a[2][0]); a[2][1] = fmaf(w.y, h1v.y, a[2][1]);
            a[2][0] = fmaf(w.z, h2v.x, a[2][0]); a[2][1] = fmaf(w.z, h2v.y, a[2][1]);
            a[2][0] = fmaf(w.w, h3v.x, a[2][0]); a[2][1] = fmaf(w.w, h3v.y, a[2][1]);
            w = *reinterpret_cast<const float4*>(wO + q * 4);
            a[3][0] = fmaf(w.x, h0v.x, a[3][0]); a[3][1] = fmaf(w.x, h0v.y, a[3][1]);
            a[3][0] = fmaf(w.y, h1v.x, a[3][0]); a[3][1] = fmaf(w.y, h1v.y, a[3][1]);
            a[3][0] = fmaf(w.z, h2v.x, a[3][0]); a[3][1] = fmaf(w.z, h2v.y, a[3][1]);
            a[3][0] = fmaf(w.w, h3v.x, a[3][0]); a[3][1] = fmaf(w.w, h3v.y, a[3][1]);
        }
    }
    #pragma unroll
    for (int gg = 0; gg < 4; ++gg) {
        pre[ks][gg][2 * bg]     = a[gg][0];
        pre[ks][gg][2 * bg + 1] = a[gg][1];
    }
    __syncthreads();

    if (tid < 128) {
        int gg = tid >> 5;
        int b  = tid & 31;
        float s = 0.f;
        #pragma unroll
        for (int k2 = 0; k2 < 16; ++k2) s += pre[k2][gg][b];
        s += Z[((size_t)(t * 4 + gg) * HH + h) * BB + b];
        if (t > 0) {
            const float* bp = (gg == 0) ? bf : (gg == 1) ? bi : (gg == 2) ? bc : bo;
            s += bp[t * HH + h];
        }
        act[gg][b] = (gg == 2) ? tanhf(s) : 1.f / (1.f + __expf(-s));
    }
    __syncthreads();

    if (tid < 32) {
        int b = tid;
        float cold = (t > 0) ? C[h * BB + b] : 0.f;
        float cn = act[0][b] * cold + act[1][b] * act[2][b];
        C[h * BB + b] = cn;
        float hn = act[3][b] * tanhf(cn);
        Hall[((size_t)t * HH + h) * BB + b] = hn;
    }
}

// ---------------- Phase C: logits[b][t][v] = Hall[t][:][b] . lin_w[t][v][:] + lin_b[t][v] ----
__global__ __launch_bounds__(256) void phaseC_kernel(
    const float* __restrict__ lw, const float* __restrict__ lb,
    const float* __restrict__ Hall, float* __restrict__ out)
{
    int t  = blockIdx.x >> 2;
    int v0 = (blockIdx.x & 3) << 5;
    int tid = threadIdx.x;
    int v  = v0 + (tid >> 3);
    int bg = tid & 7;
    const float* w  = lw + ((size_t)t * VV + v) * HH;
    const float* hp = Hall + (size_t)t * HH * BB;
    float acc0 = 0.f, acc1 = 0.f, acc2 = 0.f, acc3 = 0.f;
    #pragma unroll 4
    for (int k = 0; k < HH; ++k) {
        float wv = w[k];
        float4 hv = *reinterpret_cast<const float4*>(hp + (size_t)k * BB + bg * 4);
        acc0 = fmaf(wv, hv.x, acc0);
        acc1 = fmaf(wv, hv.y, acc1);
        acc2 = fmaf(wv, hv.z, acc2);
        acc3 = fmaf(wv, hv.w, acc3);
    }
    float bias = lb[t * VV + v];
    float r[4] = {acc0 + bias, acc1 + bias, acc2 + bias, acc3 + bias};
    #pragma unroll
    for (int j = 0; j < 4; ++j) {
        int b = bg * 4 + j;
        out[((size_t)b * TT + t) * VV + v] = r[j];
    }
}

extern "C" void kernel_launch(void* const* d_in, const int* in_sizes, int n_in,
                              void* d_out, int out_size, void* d_ws, size_t ws_size,
                              hipStream_t stream)
{
    const float* x     = (const float*)d_in[0];
    const float* Wif   = (const float*)d_in[1];
    const float* Wii   = (const float*)d_in[2];
    const float* Wic   = (const float*)d_in[3];
    const float* Wio   = (const float*)d_in[4];
    const float* Whf_w = (const float*)d_in[5];
    const float* Whf_b = (const float*)d_in[6];
    const float* Whi_w = (const float*)d_in[7];
    const float* Whi_b = (const float*)d_in[8];
    const float* Whc_w = (const float*)d_in[9];
    const float* Whc_b = (const float*)d_in[10];
    const float* Who_w = (const float*)d_in[11];
    const float* Who_b = (const float*)d_in[12];
    const float* lin_w = (const float*)d_in[13];
    const float* lin_b = (const float*)d_in[14];
    float* out = (float*)d_out;

    float* Z    = (float*)d_ws;                              // 96*4*512*32 floats
    float* Hall = Z + (size_t)TT * 4 * HH * BB;              // 96*512*32 floats
    float* C    = Hall + (size_t)TT * HH * BB;               // 512*32 floats

    phaseA_kernel<<<dim3(TT * 16), dim3(256), 0, stream>>>(x, Wif, Wii, Wic, Wio, Z);

    for (int t = 0; t < TT; ++t) {
        lstm_step_kernel<<<dim3(512), dim3(256), 0, stream>>>(
            Whf_w, Whi_w, Whc_w, Who_w, Whf_b, Whi_b, Whc_b, Who_b, Z, C, Hall, t);
    }

    phaseC_kernel<<<dim3(TT * 4), dim3(256), 0, stream>>>(lin_w, lin_b, Hall, out);
}